// Round 12
// baseline (414.818 us; speedup 1.0000x reference)
//
#include <hip/hip_runtime.h>
#include <hip/hip_bf16.h>
#include <math.h>
#include <stdint.h>

#define NN 2048
#define DD 512
#define EE 65536
#define EPSV 0.5f
#define SEN 2048  // covered-rank sentinel (= n in the reference)
#define PADE 98304  // padded edge capacity per direction

static const size_t SZ = (size_t)NN * NN;  // 4,194,304

// ---------------------------------------------------------------------------
// Dense adjacency accumulation (only job left for the multi-block edge pass).
// ---------------------------------------------------------------------------
__global__ __launch_bounds__(256) void build_adj(const int* __restrict__ row,
                                                 const int* __restrict__ col,
                                                 const float* __restrict__ attr,
                                                 float* __restrict__ adj) {
  int e = blockIdx.x * 256 + threadIdx.x;  // E exact multiple of 256
  atomicAdd(&adj[row[e] * NN + col[e]], attr[e]);
}

// ---------------------------------------------------------------------------
// Fused front-end + MIS, ONE single-block kernel (1024 threads):
//   P0: cache all 64 edges/thread in regs; LDS-count degree/cdeg/rowsum
//   P1: interleaved dual Hillis-Steele scan (pad16) -> CSR/CSC row pointers
//   P2: CSR/CSC fill (LDS cursors + global u16 stores) + self-edge padding
//       (exact: prop_min keeps self; OR to self idempotent)
//   P3: init MIS state; zero global packed/counts; write rowsum
//   P4: worklist MIS rounds, 4 barriers/round:
//       R0 reset | A min-hop0 scatter | CDE min-hop1 gather + delta detect
//       + OR-hop0 scatter (dly write-only here -> exact) | GH OR-hop1 gather
//       + fold + survivor-list rebuild
//   P5: emit mis_flag/mis_list/misinv/mis_count
// Exactness: list membership == reference gates; delta-OR exact by monotone
// mask + union homomorphism; hop snapshots preserved (gathers never write
// the array they read); covered relays reset to SEN each R0.
// ---------------------------------------------------------------------------
__global__ __launch_bounds__(1024) void fused_mis(
    const int* __restrict__ row, const int* __restrict__ col,
    const float* __restrict__ attr, const int* __restrict__ rank_g,
    unsigned short* __restrict__ colidx, unsigned short* __restrict__ rowidx,
    float* __restrict__ rowsum_g, unsigned long long* __restrict__ packed,
    int* __restrict__ counts, int* __restrict__ mis_flag,
    int* __restrict__ mis_list, int* __restrict__ misinv,
    int* __restrict__ mis_count) {
  __shared__ int rank_s[NN];
  __shared__ int mr[NN];        // P0-P2: degree
  __shared__ int cov[NN];       // P0-P2: cdeg
  __shared__ int dly[NN];       // P1: scan buf / P2: CSR cursor
  __shared__ int mis_s[NN];     // P0: rowsum(f32) / P1: scan buf / P2: CSC cursor
  __shared__ int row_ptr_s[NN + 1];
  __shared__ int col_ptr_s[NN + 1];
  __shared__ int unc[2][NN];    // P1: scan bufs / P4: worklists
  __shared__ int ucnt[2];
  __shared__ int cnt;
  int t = threadIdx.x;
  float* rowsum_s = (float*)mis_s;

  // --- P0: zero counters, cache edges, count degrees + rowsum ---
  for (int v = t; v < NN; v += 1024) {
    mr[v] = 0;
    cov[v] = 0;
    rowsum_s[v] = 0.f;
  }
  __syncthreads();
  unsigned pe[64];
#pragma unroll
  for (int i = 0; i < 64; ++i) {
    int e = t + 1024 * i;  // coalesced
    int r = row[e], c = col[e];
    pe[i] = ((unsigned)r << 11) | (unsigned)c;
    atomicAdd(&mr[r], 1);
    atomicAdd(&cov[c], 1);
    atomicAdd(&rowsum_s[r], attr[e]);
  }
  __syncthreads();

  // --- P1: write rowsum to global; dual scan of pad16(deg), pad16(cdeg) ---
  int* s1 = dly;    int* d1 = mis_s;
  int* s2 = unc[0]; int* d2 = unc[1];
  for (int v = t; v < NN; v += 1024) {
    rowsum_g[v] = rowsum_s[v];           // read mis_s BEFORE scan clobbers it
    s1[v] = (mr[v] + 15) & ~15;
    s2[v] = (cov[v] + 15) & ~15;
  }
  __syncthreads();
  for (int off = 1; off < NN; off <<= 1) {
    for (int v = t; v < NN; v += 1024) {
      d1[v] = s1[v] + (v >= off ? s1[v - off] : 0);
      d2[v] = s2[v] + (v >= off ? s2[v - off] : 0);
    }
    __syncthreads();
    int* tp = s1; s1 = d1; d1 = tp;
    tp = s2; s2 = d2; d2 = tp;
  }
  for (int v = t; v < NN; v += 1024) {
    int end = s1[v];
    row_ptr_s[v] = end - ((mr[v] + 15) & ~15);
    end = s2[v];
    col_ptr_s[v] = end - ((cov[v] + 15) & ~15);
  }
  if (t == 0) {
    row_ptr_s[NN] = s1[NN - 1];
    col_ptr_s[NN] = s2[NN - 1];
  }
  __syncthreads();

  // --- P2: self-pad + cursors, then edge fill ---
  for (int v = t; v < NN; v += 1024) {
    int e0 = row_ptr_s[v];
    dly[v] = e0;                          // CSR cursor (scan bufs now free)
    for (int e = e0 + mr[v]; e < row_ptr_s[v + 1]; ++e)
      colidx[e] = (unsigned short)v;
    e0 = col_ptr_s[v];
    mis_s[v] = e0;                        // CSC cursor
    for (int e = e0 + cov[v]; e < col_ptr_s[v + 1]; ++e)
      rowidx[e] = (unsigned short)v;
  }
  __syncthreads();
#pragma unroll
  for (int i = 0; i < 64; ++i) {
    unsigned p = pe[i];
    int r = p >> 11, c = p & 2047;
    colidx[atomicAdd(&dly[r], 1)] = (unsigned short)c;
    rowidx[atomicAdd(&mis_s[c], 1)] = (unsigned short)r;
  }
  __syncthreads();  // drains global stores (vmcnt) before P4 reads them

  // --- P3: init MIS state + zero global packed/counts ---
  for (int v = t; v < NN; v += 1024) {
    int rk = rank_g[v];
    rank_s[v] = rk;
    mr[v] = rk;
    cov[v] = 0;
    dly[v] = 0;
    mis_s[v] = 0;
    unc[0][v] = v;
    packed[v] = 0ull;
    counts[v] = 0;
  }
  if (t == 0) {
    ucnt[0] = NN;
    ucnt[1] = 0;
    cnt = 0;
  }
  __syncthreads();

  const uint4* col4 = (const uint4*)colidx;  // 8 u16 per uint4
  const uint4* row4 = (const uint4*)rowidx;

  // --- P4: worklist MIS rounds ---
  int cur = 0;
  for (int round = 0; round < NN; ++round) {
    int U = ucnt[cur];
    if (round) {  // R0: batched reset (pure stores + 2 cov reads/thread)
      for (int v = t; v < NN; v += 1024) {
        mr[v] = cov[v] ? SEN : rank_s[v];
        dly[v] = 0;
      }
      if (t == 0) ucnt[cur ^ 1] = 0;
      __syncthreads();
    }
    // A: min hop0 scatter from uncovered sources
    for (int i = t; i < U; i += 1024) {
      int v = unc[cur][i];
      int val = rank_s[v];
      int e0 = row_ptr_s[v];
      int nch = (row_ptr_s[v + 1] - e0) >> 3;
      const uint4* b4 = col4 + (e0 >> 3);
      for (int cI = 0; cI < nch; cI += 2) {
        uint4 A = b4[cI], B = b4[cI + 1];
        atomicMin(&mr[A.x & 0xFFFFu], val); atomicMin(&mr[A.x >> 16], val);
        atomicMin(&mr[A.y & 0xFFFFu], val); atomicMin(&mr[A.y >> 16], val);
        atomicMin(&mr[A.z & 0xFFFFu], val); atomicMin(&mr[A.z >> 16], val);
        atomicMin(&mr[A.w & 0xFFFFu], val); atomicMin(&mr[A.w >> 16], val);
        atomicMin(&mr[B.x & 0xFFFFu], val); atomicMin(&mr[B.x >> 16], val);
        atomicMin(&mr[B.y & 0xFFFFu], val); atomicMin(&mr[B.y >> 16], val);
        atomicMin(&mr[B.z & 0xFFFFu], val); atomicMin(&mr[B.z >> 16], val);
        atomicMin(&mr[B.w & 0xFFFFu], val); atomicMin(&mr[B.w >> 16], val);
      }
    }
    __syncthreads();
    // CDE: min hop1 gather (CSC) + delta detect + OR hop0 scatter (dly
    // write-only in this phase -> no snapshot hazard)
    for (int i = t; i < U; i += 1024) {
      int v = unc[cur][i];
      int val = mr[v];
      int e0 = col_ptr_s[v];
      int nch = (col_ptr_s[v + 1] - e0) >> 3;
      const uint4* b4 = row4 + (e0 >> 3);
      for (int cI = 0; cI < nch; cI += 2) {
        uint4 A = b4[cI], B = b4[cI + 1];
        int m0 = min(mr[A.x & 0xFFFFu], mr[A.x >> 16]);
        int m1 = min(mr[A.y & 0xFFFFu], mr[A.y >> 16]);
        int m2 = min(mr[A.z & 0xFFFFu], mr[A.z >> 16]);
        int m3 = min(mr[A.w & 0xFFFFu], mr[A.w >> 16]);
        int m4 = min(mr[B.x & 0xFFFFu], mr[B.x >> 16]);
        int m5 = min(mr[B.y & 0xFFFFu], mr[B.y >> 16]);
        int m6 = min(mr[B.z & 0xFFFFu], mr[B.z >> 16]);
        int m7 = min(mr[B.w & 0xFFFFu], mr[B.w >> 16]);
        val = min(val, min(min(min(m0, m1), min(m2, m3)),
                           min(min(m4, m5), min(m6, m7))));
      }
      if (rank_s[v] == val) {  // newly selected: keep-self + out-scatter
        mis_s[v] = 1;
        dly[v] = 1;
        int f0 = row_ptr_s[v];
        int fch = (row_ptr_s[v + 1] - f0) >> 3;
        const uint4* c4 = col4 + (f0 >> 3);
        for (int cI = 0; cI < fch; cI += 2) {
          uint4 A = c4[cI], B = c4[cI + 1];
          dly[A.x & 0xFFFFu] = 1; dly[A.x >> 16] = 1;
          dly[A.y & 0xFFFFu] = 1; dly[A.y >> 16] = 1;
          dly[A.z & 0xFFFFu] = 1; dly[A.z >> 16] = 1;
          dly[A.w & 0xFFFFu] = 1; dly[A.w >> 16] = 1;
          dly[B.x & 0xFFFFu] = 1; dly[B.x >> 16] = 1;
          dly[B.y & 0xFFFFu] = 1; dly[B.y >> 16] = 1;
          dly[B.z & 0xFFFFu] = 1; dly[B.z >> 16] = 1;
          dly[B.w & 0xFFFFu] = 1; dly[B.w >> 16] = 1;
        }
      }
    }
    __syncthreads();
    // GH: OR hop1 gather (CSC) + fold + survivor-list rebuild
    for (int i = t; i < U; i += 1024) {
      int v = unc[cur][i];
      int c1 = dly[v];
      if (!c1) {
        int e0 = col_ptr_s[v];
        int nch = (col_ptr_s[v + 1] - e0) >> 3;
        const uint4* b4 = row4 + (e0 >> 3);
        for (int cI = 0; cI < nch; cI += 2) {
          uint4 A = b4[cI], B = b4[cI + 1];
          c1 |= dly[A.x & 0xFFFFu] | dly[A.x >> 16] |
                dly[A.y & 0xFFFFu] | dly[A.y >> 16] |
                dly[A.z & 0xFFFFu] | dly[A.z >> 16] |
                dly[A.w & 0xFFFFu] | dly[A.w >> 16] |
                dly[B.x & 0xFFFFu] | dly[B.x >> 16] |
                dly[B.y & 0xFFFFu] | dly[B.y >> 16] |
                dly[B.z & 0xFFFFu] | dly[B.z >> 16] |
                dly[B.w & 0xFFFFu] | dly[B.w >> 16];
          if (c1) break;
        }
      }
      if (c1) cov[v] = 1;
      else unc[cur ^ 1][atomicAdd(&ucnt[cur ^ 1], 1)] = v;
    }
    __syncthreads();
    if (ucnt[cur ^ 1] == 0) break;
    cur ^= 1;
  }

  // --- P5: emit MIS outputs ---
  for (int v = t; v < NN; v += 1024) {
    int s = mis_s[v];
    mis_flag[v] = s;
    int slot = -1;
    if (s) {
      slot = atomicAdd(&cnt, 1);  // unordered: all consumers order-free
      mis_list[slot] = v;
    }
    misinv[v] = slot;
  }
  __syncthreads();
  if (t == 0) *mis_count = cnt;
}

// ---------------------------------------------------------------------------
// adj -> rw in place, fused with MIS-column gather into compact Bc and
// out_xp zeroing (replaces a memset node).
// ---------------------------------------------------------------------------
__global__ __launch_bounds__(256) void rw_transform_gather(float* __restrict__ adj,
                                                           const float* __restrict__ rowsum,
                                                           const int* __restrict__ misinv,
                                                           float* __restrict__ Bc,
                                                           float* __restrict__ out_xp) {
  int idx = blockIdx.x * 256 + threadIdx.x;  // over N*N
  int i = idx >> 11, j = idx & (NN - 1);
  float s = rowsum[i];
  s = (s > 0.f) ? s : 1.f;
  float v = adj[idx] / s;
  v = (i == j) ? (v + EPSV) : (v * (1.f - EPSV));
  adj[idx] = v;
  int tc = misinv[j];
  if (tc >= 0) Bc[(size_t)tc * NN + i] = v;
  if (idx < NN * DD) out_xp[idx] = 0.f;
}

// ---------------------------------------------------------------------------
// Fused c2 + Gumbel-argmax (round-9/11 form: 4 cols/job, 1024 blocks).
// ---------------------------------------------------------------------------
__device__ inline unsigned int f32_key(float x) {
  unsigned int u = __float_as_uint(x);
  return (u & 0x80000000u) ? ~u : (u | 0x80000000u);
}
__device__ inline float dot4(float4 a, float4 b) {
  return ((a.x * b.x + a.y * b.y) + (a.z * b.z + a.w * b.w));
}
__device__ inline unsigned long long umax64(unsigned long long a, unsigned long long b) {
  return a > b ? a : b;
}
__device__ inline int pdecode(unsigned long long p) {
  return (p == 0ull) ? 0 : (NN - 1 - (int)(p & 0xFFFFFFFFull));
}

__global__ __launch_bounds__(256) void c2_argmax(const float* __restrict__ rw,
                                                 const float* __restrict__ Bc,
                                                 const float* __restrict__ u,
                                                 const int* __restrict__ mis_list,
                                                 const int* __restrict__ mis_count,
                                                 unsigned long long* __restrict__ packed) {
  int M = *mis_count;
  int ncg = (M + 3) >> 2;
  int njobs = ncg * 64;  // 64 tiles of 32 rows
  int lane = threadIdx.x & 63, w = threadIdx.x >> 6;
  for (int j = blockIdx.x; j < njobs; j += gridDim.x) {
    int cg = j >> 6, tile = j & 63;
    int c0 = cg * 4;
    float4 creg[4][8];
    int mcol[4];
#pragma unroll
    for (int cc = 0; cc < 4; ++cc) {
      int colv = c0 + cc;
      int cl = colv < M ? colv : (M - 1);
      mcol[cc] = mis_list[cl];
      const float4* cb = (const float4*)(Bc + (size_t)cl * NN);
#pragma unroll
      for (int q = 0; q < 8; ++q) creg[cc][q] = cb[q * 64 + lane];
    }
    int rbase = tile * 32 + w * 8;
#pragma unroll
    for (int it = 0; it < 8; ++it) {
      int r = rbase + it;
      const float4* rp = (const float4*)(rw + (size_t)r * NN);
      float4 a0 = rp[lane], a1 = rp[64 + lane], a2 = rp[128 + lane], a3 = rp[192 + lane];
      float4 a4 = rp[256 + lane], a5 = rp[320 + lane], a6 = rp[384 + lane], a7 = rp[448 + lane];
      float sacc[4];
#pragma unroll
      for (int cc = 0; cc < 4; ++cc) {
        float s01 = dot4(a0, creg[cc][0]) + dot4(a1, creg[cc][1]);
        float s23 = dot4(a2, creg[cc][2]) + dot4(a3, creg[cc][3]);
        float s45 = dot4(a4, creg[cc][4]) + dot4(a5, creg[cc][5]);
        float s67 = dot4(a6, creg[cc][6]) + dot4(a7, creg[cc][7]);
        float s = (s01 + s23) + (s45 + s67);
        s += __shfl_xor(s, 32);
        s += __shfl_xor(s, 16);
        s += __shfl_xor(s, 8);
        s += __shfl_xor(s, 4);
        s += __shfl_xor(s, 2);
        s += __shfl_xor(s, 1);
        sacc[cc] = s;
      }
      if (lane == 0) {
        unsigned long long best = 0ull;
#pragma unroll
        for (int cc = 0; cc < 4; ++cc) {
          if (c0 + cc < M && sacc[cc] > 0.f) {
            int m = mcol[cc];
            float uu = u[(size_t)r * NN + m];
            float g = -logf(-logf(uu + 1e-20f) + 1e-20f);
            float logit = logf(sacc[cc]) + g;
            unsigned long long key =
                ((unsigned long long)f32_key(logit) << 32) | (unsigned int)(NN - 1 - m);
            best = umax64(best, key);
          }
        }
        if (best) atomicMax(&packed[r], best);
      }
    }
  }
}

// ---------------------------------------------------------------------------
// Fused: inline winner decode + cluster/counts + adj_c scatter + x_pool
// scatter (cluster_decode dispatch deleted; proven exact in round 10).
// ---------------------------------------------------------------------------
__global__ __launch_bounds__(256) void scatter_fused(const int* __restrict__ row,
                                                     const int* __restrict__ col,
                                                     const float* __restrict__ attr,
                                                     const float* __restrict__ x,
                                                     const unsigned long long* __restrict__ packed,
                                                     int* __restrict__ cluster,
                                                     int* __restrict__ counts,
                                                     float* __restrict__ adjc,
                                                     float* __restrict__ xp) {
  int idx = blockIdx.x * 256 + threadIdx.x;  // over N*D (= 1,048,576)
  int i = idx >> 9;
  int ci = pdecode(packed[i]);  // broadcast within each 512-thread row group
  if ((idx & 511) == 0) {
    cluster[i] = ci;
    atomicAdd(&counts[ci], 1);
  }
  if (idx < EE) {
    int cr = pdecode(packed[row[idx]]);
    int cc = pdecode(packed[col[idx]]);
    atomicAdd(&adjc[(size_t)cr * NN + cc], attr[idx]);
  }
  atomicAdd(&xp[ci * DD + (idx & (DD - 1))], x[idx]);
}

// ---------------------------------------------------------------------------
// c_hard, p_inv, mis, and x_pool scaling in one pass.
// ---------------------------------------------------------------------------
__global__ __launch_bounds__(256) void write_chpm(const int* __restrict__ cluster,
                                                  const int* __restrict__ counts,
                                                  const int* __restrict__ mis_flag,
                                                  float* __restrict__ out_ch,
                                                  float* __restrict__ out_pinv,
                                                  float* __restrict__ out_mis,
                                                  float* __restrict__ out_xp) {
  int idx = blockIdx.x * 256 + threadIdx.x;  // over N*N
  int a = idx >> 11, b = idx & (NN - 1);
  out_ch[idx] = (cluster[a] == b) ? 1.f : 0.f;
  float pv = 0.f;
  if (cluster[b] == a) {
    int c = counts[a];
    pv = 1.f / (float)(c > 0 ? c : 1);
  }
  out_pinv[idx] = pv;
  if (idx < NN) out_mis[idx] = mis_flag[idx] ? 1.f : 0.f;
  if (idx < NN * DD) {
    int c = counts[idx >> 9];
    out_xp[idx] = out_xp[idx] / (float)(c > 0 ? c : 1);
  }
}

// ---------------------------------------------------------------------------
extern "C" void kernel_launch(void* const* d_in, const int* in_sizes, int n_in,
                              void* d_out, int out_size, void* d_ws, size_t ws_size,
                              hipStream_t stream) {
  const int*   edge_index = (const int*)d_in[0];
  const float* edge_attr  = (const float*)d_in[1];
  const float* x          = (const float*)d_in[2];
  const int*   rank       = (const int*)d_in[3];
  const float* u          = (const float*)d_in[4];
  float* out              = (float*)d_out;  // f32 outputs, concatenated

  const int* row = edge_index;
  const int* col = edge_index + EE;

  float* out_adjc = out;                 // N*N — doubles as adj/rw scratch
  float* out_ch   = out + SZ;            // N*N — doubles as Bc scratch
  float* out_pinv = out + 2 * SZ;        // N*N
  float* out_mis  = out + 3 * SZ;        // N
  float* out_xp   = out + 3 * SZ + NN;   // N*D

  // d_ws layout (~460 KB). packed/counts zeroed inside fused_mis; no ws memset.
  unsigned long long* packed = (unsigned long long*)d_ws;  // N u64
  float* rowsum    = (float*)(packed + NN);        // N
  int*   counts    = (int*)(rowsum + NN);          // N
  int*   mis_flag  = counts + NN;                  // N
  int*   cluster   = mis_flag + NN;                // N
  int*   mis_list  = cluster + NN;                 // N
  int*   misinv    = mis_list + NN;                // N
  int*   mis_count = misinv + NN;                  // 1
  unsigned short* colidx =                          // PADE u16, 32B-aligned
      (unsigned short*)(((uintptr_t)(mis_count + 1) + 31) & ~(uintptr_t)31);
  unsigned short* rowidx = colidx + PADE;          // PADE u16 (32B-aligned)

  hipMemsetAsync(out_adjc, 0, SZ * sizeof(float), stream);  // adj accumulator
  build_adj<<<EE / 256, 256, 0, stream>>>(row, col, edge_attr, out_adjc);
  fused_mis<<<1, 1024, 0, stream>>>(row, col, edge_attr, rank, colidx, rowidx,
                                    rowsum, packed, counts, mis_flag, mis_list,
                                    misinv, mis_count);
  rw_transform_gather<<<(NN * NN) / 256, 256, 0, stream>>>(out_adjc, rowsum, misinv,
                                                           out_ch, out_xp);
  c2_argmax<<<1024, 256, 0, stream>>>(out_adjc, out_ch, u, mis_list, mis_count, packed);

  // rw no longer needed: rewrite the region with the real adj_c
  hipMemsetAsync(out_adjc, 0, SZ * sizeof(float), stream);
  scatter_fused<<<(NN * DD) / 256, 256, 0, stream>>>(row, col, edge_attr, x, packed,
                                                     cluster, counts, out_adjc, out_xp);

  write_chpm<<<(NN * NN) / 256, 256, 0, stream>>>(cluster, counts, mis_flag,
                                                  out_ch, out_pinv, out_mis, out_xp);
}

// Round 13
// 243.560 us; speedup vs baseline: 1.7031x; 1.7031x over previous
//
#include <hip/hip_runtime.h>
#include <hip/hip_bf16.h>
#include <math.h>
#include <stdint.h>

#define NN 2048
#define DD 512
#define EE 65536
#define EPSV 0.5f
#define SEN 2048   // covered-rank sentinel (= n in the reference)
#define PADE 98304 // padded edge capacity per direction

static const size_t SZ = (size_t)NN * NN;  // 4,194,304

// ---------------------------------------------------------------------------
// Degree counting only (multi-block; inputs zeroed by the 16KB ws memset).
// ---------------------------------------------------------------------------
__global__ __launch_bounds__(256) void count_deg(const int* __restrict__ row,
                                                 const int* __restrict__ col,
                                                 int* __restrict__ degree,
                                                 int* __restrict__ cdeg) {
  int e = blockIdx.x * 256 + threadIdx.x;  // E exact multiple of 256
  atomicAdd(&degree[row[e]], 1);
  atomicAdd(&cdeg[col[e]], 1);
}

// ---------------------------------------------------------------------------
// Dual CSR/CSC scan + self-edge padding (interleaved Hillis-Steele, 1 block).
// Pads: CSR gets self-edges with avals=0 (exact: +0 to adj/rowsum; prop_min
// keeps self; OR to self idempotent). Also zeroes global packed/counts so no
// separate ws memset is needed for them.
// ---------------------------------------------------------------------------
__global__ __launch_bounds__(1024) void csr_scan_pad(const int* __restrict__ degree,
                                                     const int* __restrict__ cdeg,
                                                     int* __restrict__ row_ptr,
                                                     int* __restrict__ fill_ptr,
                                                     int* __restrict__ col_ptr,
                                                     int* __restrict__ cfill_ptr,
                                                     unsigned short* __restrict__ colidx,
                                                     unsigned short* __restrict__ rowidx,
                                                     float* __restrict__ avals,
                                                     unsigned long long* __restrict__ packed,
                                                     int* __restrict__ counts) {
  __shared__ int a[NN], b[NN], c[NN], d[NN];
  int t = threadIdx.x;
  for (int v = t; v < NN; v += 1024) {
    a[v] = (degree[v] + 15) & ~15;
    c[v] = (cdeg[v] + 15) & ~15;
    packed[v] = 0ull;
    counts[v] = 0;
  }
  __syncthreads();
  int* s1 = a; int* d1 = b; int* s2 = c; int* d2 = d;
  for (int off = 1; off < NN; off <<= 1) {
    for (int v = t; v < NN; v += 1024) {
      d1[v] = s1[v] + (v >= off ? s1[v - off] : 0);
      d2[v] = s2[v] + (v >= off ? s2[v - off] : 0);
    }
    __syncthreads();
    int* tp = s1; s1 = d1; d1 = tp;
    tp = s2; s2 = d2; d2 = tp;
  }
  for (int v = t; v < NN; v += 1024) {
    int dg = degree[v];
    int end = s1[v];
    int excl = end - ((dg + 15) & ~15);
    row_ptr[v] = excl;
    fill_ptr[v] = excl;
    for (int e = excl + dg; e < end; ++e) {  // CSR self pad, zero weight
      colidx[e] = (unsigned short)v;
      avals[e] = 0.f;
    }
    dg = cdeg[v];
    end = s2[v];
    excl = end - ((dg + 15) & ~15);
    col_ptr[v] = excl;
    cfill_ptr[v] = excl;
    for (int e = excl + dg; e < end; ++e) rowidx[e] = (unsigned short)v;  // CSC self pad
  }
  if (t == 0) {
    row_ptr[NN] = s1[NN - 1];
    col_ptr[NN] = s2[NN - 1];
  }
}

__global__ __launch_bounds__(256) void csr_fill(const int* __restrict__ row,
                                                const int* __restrict__ col,
                                                const float* __restrict__ attr,
                                                int* __restrict__ fill_ptr,
                                                int* __restrict__ cfill_ptr,
                                                unsigned short* __restrict__ colidx,
                                                unsigned short* __restrict__ rowidx,
                                                float* __restrict__ avals) {
  int e = blockIdx.x * 256 + threadIdx.x;
  int r = row[e], c = col[e];
  int pos = atomicAdd(&fill_ptr[r], 1);
  colidx[pos] = (unsigned short)c;
  avals[pos] = attr[e];
  rowidx[atomicAdd(&cfill_ptr[c], 1)] = (unsigned short)r;
}

// ---------------------------------------------------------------------------
// Greedy maximal k-independent set (k=2) — VERBATIM round-11 worklist kernel
// (measured 46.5µs, absmax 0). Single block, LDS state, 5 barriers/round.
// ---------------------------------------------------------------------------
__global__ __launch_bounds__(1024) void mis_kernel(const int* __restrict__ row_ptr_g,
                                                   const int* __restrict__ col_ptr_g,
                                                   const unsigned short* __restrict__ colidx,
                                                   const unsigned short* __restrict__ rowidx,
                                                   const int* __restrict__ rank_g,
                                                   int* __restrict__ mis_flag,
                                                   int* __restrict__ mis_list,
                                                   int* __restrict__ misinv,
                                                   int* __restrict__ mis_count) {
  __shared__ int rank_s[NN];
  __shared__ int mr[NN];
  __shared__ int cov[NN];
  __shared__ int dly[NN];
  __shared__ int mis_s[NN];
  __shared__ int row_ptr_s[NN + 1];
  __shared__ int col_ptr_s[NN + 1];
  __shared__ int unc[2][NN];
  __shared__ int dl[NN];
  __shared__ int ucnt[2];
  __shared__ int dcnt;
  __shared__ int cnt;
  int t = threadIdx.x;
  const uint4* col4 = (const uint4*)colidx;  // 8 u16 per uint4
  const uint4* row4 = (const uint4*)rowidx;

  for (int v = t; v < NN; v += 1024) {
    int rk = rank_g[v];
    rank_s[v] = rk;
    mr[v] = rk;
    cov[v] = 0;
    dly[v] = 0;
    mis_s[v] = 0;
    row_ptr_s[v] = row_ptr_g[v];
    col_ptr_s[v] = col_ptr_g[v];
    unc[0][v] = v;
  }
  if (t == 0) {
    row_ptr_s[NN] = row_ptr_g[NN];
    col_ptr_s[NN] = col_ptr_g[NN];
    ucnt[0] = NN;
    ucnt[1] = 0;
    dcnt = 0;
    cnt = 0;
  }
  __syncthreads();

  int cur = 0;
  for (int round = 0; round < NN; ++round) {
    int U = ucnt[cur];
    if (round) {  // R0: batched reset
      for (int v = t; v < NN; v += 1024) {
        mr[v] = cov[v] ? SEN : rank_s[v];
        dly[v] = 0;
      }
      if (t == 0) { ucnt[cur ^ 1] = 0; dcnt = 0; }
      __syncthreads();
    }
    // A: min hop0 scatter from uncovered sources
    for (int i = t; i < U; i += 1024) {
      int v = unc[cur][i];
      int val = rank_s[v];
      int e0 = row_ptr_s[v];
      int nch = (row_ptr_s[v + 1] - e0) >> 3;
      const uint4* b4 = col4 + (e0 >> 3);
      for (int cI = 0; cI < nch; cI += 2) {
        uint4 A = b4[cI], B = b4[cI + 1];
        atomicMin(&mr[A.x & 0xFFFFu], val); atomicMin(&mr[A.x >> 16], val);
        atomicMin(&mr[A.y & 0xFFFFu], val); atomicMin(&mr[A.y >> 16], val);
        atomicMin(&mr[A.z & 0xFFFFu], val); atomicMin(&mr[A.z >> 16], val);
        atomicMin(&mr[A.w & 0xFFFFu], val); atomicMin(&mr[A.w >> 16], val);
        atomicMin(&mr[B.x & 0xFFFFu], val); atomicMin(&mr[B.x >> 16], val);
        atomicMin(&mr[B.y & 0xFFFFu], val); atomicMin(&mr[B.y >> 16], val);
        atomicMin(&mr[B.z & 0xFFFFu], val); atomicMin(&mr[B.z >> 16], val);
        atomicMin(&mr[B.w & 0xFFFFu], val); atomicMin(&mr[B.w >> 16], val);
      }
    }
    __syncthreads();
    // CD: min hop1 gather (CSC) + delta detect + dl append
    for (int i = t; i < U; i += 1024) {
      int v = unc[cur][i];
      int val = mr[v];
      int e0 = col_ptr_s[v];
      int nch = (col_ptr_s[v + 1] - e0) >> 3;
      const uint4* b4 = row4 + (e0 >> 3);
      for (int cI = 0; cI < nch; cI += 2) {
        uint4 A = b4[cI], B = b4[cI + 1];
        int m0 = min(mr[A.x & 0xFFFFu], mr[A.x >> 16]);
        int m1 = min(mr[A.y & 0xFFFFu], mr[A.y >> 16]);
        int m2 = min(mr[A.z & 0xFFFFu], mr[A.z >> 16]);
        int m3 = min(mr[A.w & 0xFFFFu], mr[A.w >> 16]);
        int m4 = min(mr[B.x & 0xFFFFu], mr[B.x >> 16]);
        int m5 = min(mr[B.y & 0xFFFFu], mr[B.y >> 16]);
        int m6 = min(mr[B.z & 0xFFFFu], mr[B.z >> 16]);
        int m7 = min(mr[B.w & 0xFFFFu], mr[B.w >> 16]);
        val = min(val, min(min(min(m0, m1), min(m2, m3)),
                           min(min(m4, m5), min(m6, m7))));
      }
      if (rank_s[v] == val) {
        mis_s[v] = 1;
        dly[v] = 1;  // keep-self of OR hop0
        dl[atomicAdd(&dcnt, 1)] = v;  // unordered (consumers order-free)
      }
    }
    __syncthreads();
    // E: OR hop0 scatter from delta
    int D = dcnt;
    for (int i = t; i < D; i += 1024) {
      int v = dl[i];
      int e0 = row_ptr_s[v];
      int nch = (row_ptr_s[v + 1] - e0) >> 3;
      const uint4* b4 = col4 + (e0 >> 3);
      for (int cI = 0; cI < nch; cI += 2) {
        uint4 A = b4[cI], B = b4[cI + 1];
        dly[A.x & 0xFFFFu] = 1; dly[A.x >> 16] = 1;
        dly[A.y & 0xFFFFu] = 1; dly[A.y >> 16] = 1;
        dly[A.z & 0xFFFFu] = 1; dly[A.z >> 16] = 1;
        dly[A.w & 0xFFFFu] = 1; dly[A.w >> 16] = 1;
        dly[B.x & 0xFFFFu] = 1; dly[B.x >> 16] = 1;
        dly[B.y & 0xFFFFu] = 1; dly[B.y >> 16] = 1;
        dly[B.z & 0xFFFFu] = 1; dly[B.z >> 16] = 1;
        dly[B.w & 0xFFFFu] = 1; dly[B.w >> 16] = 1;
      }
    }
    __syncthreads();
    // GH: OR hop1 gather (CSC) + fold + survivor-list rebuild
    for (int i = t; i < U; i += 1024) {
      int v = unc[cur][i];
      int c1 = dly[v];
      if (!c1) {
        int e0 = col_ptr_s[v];
        int nch = (col_ptr_s[v + 1] - e0) >> 3;
        const uint4* b4 = row4 + (e0 >> 3);
        for (int cI = 0; cI < nch; cI += 2) {
          uint4 A = b4[cI], B = b4[cI + 1];
          c1 |= dly[A.x & 0xFFFFu] | dly[A.x >> 16] |
                dly[A.y & 0xFFFFu] | dly[A.y >> 16] |
                dly[A.z & 0xFFFFu] | dly[A.z >> 16] |
                dly[A.w & 0xFFFFu] | dly[A.w >> 16] |
                dly[B.x & 0xFFFFu] | dly[B.x >> 16] |
                dly[B.y & 0xFFFFu] | dly[B.y >> 16] |
                dly[B.z & 0xFFFFu] | dly[B.z >> 16] |
                dly[B.w & 0xFFFFu] | dly[B.w >> 16];
          if (c1) break;
        }
      }
      if (c1) cov[v] = 1;
      else unc[cur ^ 1][atomicAdd(&ucnt[cur ^ 1], 1)] = v;
    }
    __syncthreads();
    if (ucnt[cur ^ 1] == 0) break;
    cur ^= 1;
  }

  for (int v = t; v < NN; v += 1024) {
    int s = mis_s[v];
    mis_flag[v] = s;
    int slot = -1;
    if (s) {
      slot = atomicAdd(&cnt, 1);
      mis_list[slot] = v;
    }
    misinv[v] = slot;
  }
  __syncthreads();
  if (t == 0) *mis_count = cnt;
}

// ---------------------------------------------------------------------------
// rw built directly from the (padded) CSR: one block per row. Replaces
// memset + dense edge-scatter + transform round-trip. LDS rowbuf accumulates
// duplicate edges (fp order differs from reference — within tolerance);
// rowsum reduced in-block. Transform + compact-Bc gather fused.
// ---------------------------------------------------------------------------
__global__ __launch_bounds__(256) void rw_build(const int* __restrict__ row_ptr,
                                                const unsigned short* __restrict__ colidx,
                                                const float* __restrict__ avals,
                                                const int* __restrict__ misinv,
                                                float* __restrict__ rw,
                                                float* __restrict__ Bc) {
  int i = blockIdx.x;
  __shared__ float rowbuf[NN];
  __shared__ float ssum;
  int t = threadIdx.x;
  for (int j = t; j < NN; j += 256) rowbuf[j] = 0.f;
  if (t == 0) ssum = 0.f;
  __syncthreads();
  int e0 = row_ptr[i], e1 = row_ptr[i + 1];
  float part = 0.f;
  for (int e = e0 + t; e < e1; e += 256) {
    float a = avals[e];
    atomicAdd(&rowbuf[colidx[e]], a);
    part += a;
  }
  for (int off = 32; off; off >>= 1) part += __shfl_down(part, off);
  if ((t & 63) == 0) atomicAdd(&ssum, part);
  __syncthreads();
  float s = ssum;
  s = (s > 0.f) ? s : 1.f;
  for (int j = t; j < NN; j += 256) {
    float v = rowbuf[j] / s;
    v = (i == j) ? (v + EPSV) : (v * (1.f - EPSV));
    rw[(size_t)i * NN + j] = v;
    int tc = misinv[j];
    if (tc >= 0) Bc[(size_t)tc * NN + i] = v;
  }
}

// ---------------------------------------------------------------------------
// Fused c2 + Gumbel-argmax (round-9/11 form: 4 cols/job, 1024 blocks).
// ---------------------------------------------------------------------------
__device__ inline unsigned int f32_key(float x) {
  unsigned int u = __float_as_uint(x);
  return (u & 0x80000000u) ? ~u : (u | 0x80000000u);
}
__device__ inline float dot4(float4 a, float4 b) {
  return ((a.x * b.x + a.y * b.y) + (a.z * b.z + a.w * b.w));
}
__device__ inline unsigned long long umax64(unsigned long long a, unsigned long long b) {
  return a > b ? a : b;
}
__device__ inline int pdecode(unsigned long long p) {
  return (p == 0ull) ? 0 : (NN - 1 - (int)(p & 0xFFFFFFFFull));
}

__global__ __launch_bounds__(256) void c2_argmax(const float* __restrict__ rw,
                                                 const float* __restrict__ Bc,
                                                 const float* __restrict__ u,
                                                 const int* __restrict__ mis_list,
                                                 const int* __restrict__ mis_count,
                                                 unsigned long long* __restrict__ packed) {
  int M = *mis_count;
  int ncg = (M + 3) >> 2;
  int njobs = ncg * 64;  // 64 tiles of 32 rows
  int lane = threadIdx.x & 63, w = threadIdx.x >> 6;
  for (int j = blockIdx.x; j < njobs; j += gridDim.x) {
    int cg = j >> 6, tile = j & 63;
    int c0 = cg * 4;
    float4 creg[4][8];
    int mcol[4];
#pragma unroll
    for (int cc = 0; cc < 4; ++cc) {
      int colv = c0 + cc;
      int cl = colv < M ? colv : (M - 1);
      mcol[cc] = mis_list[cl];
      const float4* cb = (const float4*)(Bc + (size_t)cl * NN);
#pragma unroll
      for (int q = 0; q < 8; ++q) creg[cc][q] = cb[q * 64 + lane];
    }
    int rbase = tile * 32 + w * 8;
#pragma unroll
    for (int it = 0; it < 8; ++it) {
      int r = rbase + it;
      const float4* rp = (const float4*)(rw + (size_t)r * NN);
      float4 a0 = rp[lane], a1 = rp[64 + lane], a2 = rp[128 + lane], a3 = rp[192 + lane];
      float4 a4 = rp[256 + lane], a5 = rp[320 + lane], a6 = rp[384 + lane], a7 = rp[448 + lane];
      float sacc[4];
#pragma unroll
      for (int cc = 0; cc < 4; ++cc) {
        float s01 = dot4(a0, creg[cc][0]) + dot4(a1, creg[cc][1]);
        float s23 = dot4(a2, creg[cc][2]) + dot4(a3, creg[cc][3]);
        float s45 = dot4(a4, creg[cc][4]) + dot4(a5, creg[cc][5]);
        float s67 = dot4(a6, creg[cc][6]) + dot4(a7, creg[cc][7]);
        float s = (s01 + s23) + (s45 + s67);
        s += __shfl_xor(s, 32);
        s += __shfl_xor(s, 16);
        s += __shfl_xor(s, 8);
        s += __shfl_xor(s, 4);
        s += __shfl_xor(s, 2);
        s += __shfl_xor(s, 1);
        sacc[cc] = s;
      }
      if (lane == 0) {
        unsigned long long best = 0ull;
#pragma unroll
        for (int cc = 0; cc < 4; ++cc) {
          if (c0 + cc < M && sacc[cc] > 0.f) {
            int m = mcol[cc];
            float uu = u[(size_t)r * NN + m];
            float g = -logf(-logf(uu + 1e-20f) + 1e-20f);
            float logit = logf(sacc[cc]) + g;
            unsigned long long key =
                ((unsigned long long)f32_key(logit) << 32) | (unsigned int)(NN - 1 - m);
            best = umax64(best, key);
          }
        }
        if (best) atomicMax(&packed[r], best);
      }
    }
  }
}

// ---------------------------------------------------------------------------
// Zero the adjc + xp output regions AND decode winners -> cluster/counts.
// ---------------------------------------------------------------------------
__global__ __launch_bounds__(256) void decode_zero(const unsigned long long* __restrict__ packed,
                                                   int* __restrict__ cluster,
                                                   int* __restrict__ counts,
                                                   float* __restrict__ adjc,
                                                   float* __restrict__ xp) {
  int idx = blockIdx.x * 256 + threadIdx.x;  // over SZ + N*D = 5,242,880
  if (idx < (int)SZ) adjc[idx] = 0.f;
  else xp[idx - (int)SZ] = 0.f;
  if (idx < NN) {
    int m = pdecode(packed[idx]);
    cluster[idx] = m;
    atomicAdd(&counts[m], 1);
  }
}

// ---------------------------------------------------------------------------
// Final fused pass: c_hard + p_inv + mis writes, adj_c edge scatter, and
// PRE-SCALED x_pool accumulation (counts final after decode_zero, so
// sum(x/cnt) == sum(x)/cnt within fp tolerance — no separate scaling pass).
// ---------------------------------------------------------------------------
__global__ __launch_bounds__(256) void scatter_chpm(const int* __restrict__ row,
                                                    const int* __restrict__ col,
                                                    const float* __restrict__ attr,
                                                    const float* __restrict__ x,
                                                    const int* __restrict__ cluster,
                                                    const int* __restrict__ counts,
                                                    const int* __restrict__ mis_flag,
                                                    float* __restrict__ out_ch,
                                                    float* __restrict__ out_pinv,
                                                    float* __restrict__ out_mis,
                                                    float* __restrict__ adjc,
                                                    float* __restrict__ xp) {
  int idx = blockIdx.x * 256 + threadIdx.x;  // over N*N
  int a = idx >> 11, b = idx & (NN - 1);
  out_ch[idx] = (cluster[a] == b) ? 1.f : 0.f;
  float pv = 0.f;
  if (cluster[b] == a) {
    int c = counts[a];
    pv = 1.f / (float)(c > 0 ? c : 1);
  }
  out_pinv[idx] = pv;
  if (idx < NN) out_mis[idx] = mis_flag[idx] ? 1.f : 0.f;
  if (idx < NN * DD) {
    int i = idx >> 9;
    int ci = cluster[i];
    int c = counts[ci];
    atomicAdd(&xp[ci * DD + (idx & (DD - 1))], x[idx] / (float)(c > 0 ? c : 1));
  }
  if (idx < EE) {
    atomicAdd(&adjc[(size_t)cluster[row[idx]] * NN + cluster[col[idx]]], attr[idx]);
  }
}

// ---------------------------------------------------------------------------
extern "C" void kernel_launch(void* const* d_in, const int* in_sizes, int n_in,
                              void* d_out, int out_size, void* d_ws, size_t ws_size,
                              hipStream_t stream) {
  const int*   edge_index = (const int*)d_in[0];
  const float* edge_attr  = (const float*)d_in[1];
  const float* x          = (const float*)d_in[2];
  const int*   rank       = (const int*)d_in[3];
  const float* u          = (const float*)d_in[4];
  float* out              = (float*)d_out;  // f32 outputs, concatenated

  const int* row = edge_index;
  const int* col = edge_index + EE;

  float* out_adjc = out;                 // N*N — doubles as rw, then adj_c
  float* out_ch   = out + SZ;            // N*N — doubles as Bc scratch
  float* out_pinv = out + 2 * SZ;        // N*N
  float* out_mis  = out + 3 * SZ;        // N
  float* out_xp   = out + 3 * SZ + NN;   // N*D

  // d_ws layout (~850 KB). degree/cdeg zeroed by the 16KB memset;
  // packed/counts zeroed inside csr_scan_pad; rest fully written before read.
  int*   degree    = (int*)d_ws;                   // N (zeroed)
  int*   cdeg      = degree + NN;                  // N (zeroed)
  unsigned long long* packed = (unsigned long long*)(cdeg + NN);  // N u64
  int*   counts    = (int*)(packed + NN);          // N
  int*   mis_flag  = counts + NN;                  // N
  int*   cluster   = mis_flag + NN;                // N
  int*   mis_list  = cluster + NN;                 // N
  int*   misinv    = mis_list + NN;                // N
  int*   mis_count = misinv + NN;                  // 1
  int*   fill_ptr  = mis_count + 1;                // N
  int*   cfill_ptr = fill_ptr + NN;                // N
  int*   row_ptr   = cfill_ptr + NN;               // N+1
  int*   col_ptr   = row_ptr + NN + 1;             // N+1
  unsigned short* colidx =                          // PADE u16, 32B-aligned
      (unsigned short*)(((uintptr_t)(col_ptr + NN + 1) + 31) & ~(uintptr_t)31);
  unsigned short* rowidx = colidx + PADE;          // PADE u16
  float* avals = (float*)(rowidx + PADE);          // PADE f32 (CSR edge weights)

  hipMemsetAsync(d_ws, 0, 2 * NN * sizeof(int), stream);  // degree + cdeg only
  count_deg<<<EE / 256, 256, 0, stream>>>(row, col, degree, cdeg);
  csr_scan_pad<<<1, 1024, 0, stream>>>(degree, cdeg, row_ptr, fill_ptr, col_ptr,
                                       cfill_ptr, colidx, rowidx, avals, packed, counts);
  csr_fill<<<EE / 256, 256, 0, stream>>>(row, col, edge_attr, fill_ptr, cfill_ptr,
                                         colidx, rowidx, avals);
  mis_kernel<<<1, 1024, 0, stream>>>(row_ptr, col_ptr, colidx, rowidx, rank,
                                     mis_flag, mis_list, misinv, mis_count);
  rw_build<<<NN, 256, 0, stream>>>(row_ptr, colidx, avals, misinv, out_adjc, out_ch);
  c2_argmax<<<1024, 256, 0, stream>>>(out_adjc, out_ch, u, mis_list, mis_count, packed);
  decode_zero<<<(unsigned)((SZ + (size_t)NN * DD) / 256), 256, 0, stream>>>(
      packed, cluster, counts, out_adjc, out_xp);
  scatter_chpm<<<(NN * NN) / 256, 256, 0, stream>>>(row, col, edge_attr, x, cluster,
                                                    counts, mis_flag, out_ch, out_pinv,
                                                    out_mis, out_adjc, out_xp);
}